// Round 25
// baseline (703.403 us; speedup 1.0000x reference)
//
#include <hip/hip_runtime.h>
#include <hip/hip_bf16.h>
#include <stdint.h>

#define T_DIM 4096
#define K_DIM 4096
#define N_DIM 11008

#define XQ_OFF 0
#define XS_OFF 16777216
#define W8_OFF 16793600

typedef __attribute__((ext_vector_type(4))) int v4i;

// ---------------------------------------------------------------------------
// Kernel 1: FUSED quant + pack (grid-split, r21-r24-verified).
// ---------------------------------------------------------------------------
__global__ __launch_bounds__(256) void prep_kernel(
    const float* __restrict__ x, int8_t* __restrict__ xq, float* __restrict__ xs,
    const int* __restrict__ w32, int8_t* __restrict__ w8)
{
    if (blockIdx.x < T_DIM / 4) {
        const int wid   = threadIdx.x >> 6;
        const int lane  = threadIdx.x & 63;
        const int token = blockIdx.x * 4 + wid;

        const float* xrow = x + (size_t)token * K_DIM;

        float4 v[16];
        float am = 0.0f;
#pragma unroll
        for (int j = 0; j < 16; ++j) {
            v[j] = *(const float4*)(xrow + (size_t)(j * 64 + lane) * 4);
            am = fmaxf(am, fmaxf(fmaxf(fabsf(v[j].x), fabsf(v[j].y)),
                                 fmaxf(fabsf(v[j].z), fabsf(v[j].w))));
        }
#pragma unroll
        for (int m = 1; m < 64; m <<= 1)
            am = fmaxf(am, __shfl_xor(am, m, 64));

        const float scale = fmaxf(am, 1e-5f) / 127.0f;
        if (lane == 0) xs[token] = scale;

        uint32_t* qrow = (uint32_t*)(xq + (size_t)token * K_DIM);
#pragma unroll
        for (int j = 0; j < 16; ++j) {
            int q0 = min(127, max(-127, (int)rintf(v[j].x / scale)));
            int q1 = min(127, max(-127, (int)rintf(v[j].y / scale)));
            int q2 = min(127, max(-127, (int)rintf(v[j].z / scale)));
            int q3 = min(127, max(-127, (int)rintf(v[j].w / scale)));
            qrow[j * 64 + lane] = ((uint32_t)(uint8_t)(int8_t)q0)       |
                                  ((uint32_t)(uint8_t)(int8_t)q1 << 8)  |
                                  ((uint32_t)(uint8_t)(int8_t)q2 << 16) |
                                  ((uint32_t)(uint8_t)(int8_t)q3 << 24);
        }
    } else {
        const size_t tid = (size_t)(blockIdx.x - T_DIM / 4) * 256 + threadIdx.x;
        const int4* src = (const int4*)w32 + tid * 4;
        uint32_t o[4];
#pragma unroll
        for (int i = 0; i < 4; ++i) {
            int4 a = src[i];
            o[i] = ((uint32_t)a.x & 0xFFu) | (((uint32_t)a.y & 0xFFu) << 8) |
                   (((uint32_t)a.z & 0xFFu) << 16) | ((uint32_t)a.w << 24);
        }
        *(uint4*)(w8 + tid * 16) = make_uint4(o[0], o[1], o[2], o[3]);
    }
}

// ---------------------------------------------------------------------------
// Kernel 2: r24 GEMM (BK=128, 2-buf, 203us) as an ABLATION TEMPLATE.
//   V=0: full kernel (writes final out — launched LAST)
//   V=1: no MFMA (frags kept live via asm, rule #17)
//   V=2: no ds_read (constant frags, MFMA still runs)
//   V=3: no staging DMA / no vmcnt (reads stale LDS)
// Marginal dispatch durations isolate the serial cost of each pipe.
// ---------------------------------------------------------------------------
#define BM 256
#define BN 256
#define BKB 128
#define NT (K_DIM / BKB)     // 32
#define MAT_SZ 32768         // 256 rows x 128 B

template <int V>
__global__ __launch_bounds__(512, 2) void gemm_i8_kernel(
    const int8_t* __restrict__ xq, const int8_t* __restrict__ w8,
    const float* __restrict__ xs, const float* __restrict__ wsc,
    const __hip_bfloat16* __restrict__ bias, float* __restrict__ out)
{
    __shared__ int8_t lds[2 * 2 * MAT_SZ];   // 128 KiB

    constexpr int NBN = N_DIM / BN;              // 43
    constexpr int NWG = (T_DIM / BM) * NBN;      // 688
    constexpr int CPX = NWG / 8;                 // 86

    const int bid = blockIdx.x;
    const int b2  = (bid % 8) * CPX + bid / 8;
    const int bm  = b2 / NBN;
    const int bn  = b2 % NBN;

    const int tid  = threadIdx.x;
    const int wid  = tid >> 6;
    const int lane = tid & 63;
    const int wm   = wid >> 2;
    const int wn   = wid & 3;

    const int fr = lane & 15, kg = lane >> 4;
    int offA[8][2], offB[4][2];
#pragma unroll
    for (int mi = 0; mi < 8; ++mi) {
        const int row = wm * 128 + mi * 16 + fr;
#pragma unroll
        for (int ks = 0; ks < 2; ++ks)
            offA[mi][ks] = row * 128 + (((ks * 4 + kg) ^ (row & 7)) << 4);
    }
#pragma unroll
    for (int ni = 0; ni < 4; ++ni) {
        const int row = wn * 64 + ni * 16 + fr;
#pragma unroll
        for (int ks = 0; ks < 2; ++ks)
            offB[ni][ks] = row * 128 + (((ks * 4 + kg) ^ (row & 7)) << 4);
    }

    const int srow  = tid >> 3;
    const int sslot = tid & 7;
    const int csw   = (sslot ^ (srow & 7)) * 16;
    const int8_t* gA = xq + (size_t)(bm * BM + srow) * K_DIM + csw;
    const int8_t* gB = w8 + (size_t)(bn * BN + srow) * K_DIM + csw;
    const int ldsBase = (tid >> 6) * 1024;

    v4i acc[8][4];
#pragma unroll
    for (int mi = 0; mi < 8; ++mi)
#pragma unroll
        for (int ni = 0; ni < 4; ++ni) acc[mi][ni] = (v4i){0, 0, 0, 0};

#define STAGE(bufb, mat, r, kt)                                                 \
    __builtin_amdgcn_global_load_lds(                                           \
        (const __attribute__((address_space(1))) void*)(                        \
            ((mat) ? gB : gA) + (size_t)(r) * 64 * K_DIM + (size_t)(kt) * BKB), \
        (__attribute__((address_space(3))) void*)(                              \
            lds + ((bufb) * 2 + (mat)) * MAT_SZ + (r) * 8192 + ldsBase),        \
        16, 0, 0)

#define STAGE_TILE(bufb, kt)                                                    \
    do {                                                                        \
        STAGE(bufb, 0, 0, kt); STAGE(bufb, 0, 1, kt);                           \
        STAGE(bufb, 0, 2, kt); STAGE(bufb, 0, 3, kt);                           \
        STAGE(bufb, 1, 0, kt); STAGE(bufb, 1, 1, kt);                           \
        STAGE(bufb, 1, 2, kt); STAGE(bufb, 1, 3, kt);                           \
    } while (0)

    if (V != 3) {
        STAGE_TILE(0, 0);
        asm volatile("s_waitcnt vmcnt(0)" ::: "memory");
    }
    __builtin_amdgcn_s_barrier();
    asm volatile("" ::: "memory");

    for (int t = 0; t < NT; ++t) {
        const int b  = t & 1;
        const int pn = b ^ 1;
        const int8_t* bA = lds + (b * 2 + 0) * MAT_SZ;
        const int8_t* bB = lds + (b * 2 + 1) * MAT_SZ;

        if (V != 3) { if (t + 1 < NT) STAGE_TILE(pn, t + 1); }

#pragma unroll
        for (int ks = 0; ks < 2; ++ks) {
            v4i bF[4], aF[8];
            if (V != 2) {
#pragma unroll
                for (int ni = 0; ni < 4; ++ni)
                    bF[ni] = *(const v4i*)(bB + offB[ni][ks]);
#pragma unroll
                for (int mi = 0; mi < 8; ++mi)
                    aF[mi] = *(const v4i*)(bA + offA[mi][ks]);
            } else {
#pragma unroll
                for (int ni = 0; ni < 4; ++ni) bF[ni] = (v4i){ni, 1, 2, 3};
#pragma unroll
                for (int mi = 0; mi < 8; ++mi) aF[mi] = (v4i){mi, 5, 6, 7};
            }

            if (V == 1) {
                // keep ds_reads live without MFMA (rule #17 keepalive)
#pragma unroll
                for (int mi = 0; mi < 8; ++mi) asm volatile("" :: "v"(aF[mi]));
#pragma unroll
                for (int ni = 0; ni < 4; ++ni) asm volatile("" :: "v"(bF[ni]));
            } else {
                __builtin_amdgcn_s_setprio(1);
#pragma unroll
                for (int mi = 0; mi < 8; ++mi)
#pragma unroll
                    for (int ni = 0; ni < 4; ++ni)
                        acc[mi][ni] = __builtin_amdgcn_mfma_i32_16x16x64_i8(
                            aF[mi], bF[ni], acc[mi][ni], 0, 0, 0);
                __builtin_amdgcn_s_setprio(0);
            }
        }

        if (V != 3) asm volatile("s_waitcnt vmcnt(0)" ::: "memory");
        __builtin_amdgcn_s_barrier();
        asm volatile("" ::: "memory");
    }

    const int row0 = bm * BM + wm * 128 + (lane >> 4) * 4;
    const int col0 = bn * BN + wn * 64 + (lane & 15);
#pragma unroll
    for (int mi = 0; mi < 8; ++mi) {
#pragma unroll
        for (int j = 0; j < 4; ++j) {
            const int row = row0 + mi * 16 + j;
            const float xscale = xs[row];
#pragma unroll
            for (int ni = 0; ni < 4; ++ni) {
                const int col = col0 + ni * 16;
                float p_  = (float)acc[mi][ni][j] * xscale * wsc[col];
                float pb_ = __bfloat162float(__float2bfloat16(p_));
                float vb  = __bfloat162float(__float2bfloat16(
                                pb_ + __bfloat162float(bias[col])));
                out[(size_t)row * N_DIM + col] = vb;
            }
        }
    }
#undef STAGE
#undef STAGE_TILE
}

// ---------------------------------------------------------------------------
extern "C" void kernel_launch(void* const* d_in, const int* in_sizes, int n_in,
                              void* d_out, int out_size, void* d_ws, size_t ws_size,
                              hipStream_t stream)
{
    const float*          x    = (const float*)d_in[0];
    const int*            w32  = (const int*)d_in[1];
    const float*          wsc  = (const float*)d_in[2];
    const __hip_bfloat16* bias = (const __hip_bfloat16*)d_in[3];
    float*                out  = (float*)d_out;

    int8_t* xq = (int8_t*)d_ws + XQ_OFF;
    float*  xs = (float*)((char*)d_ws + XS_OFF);
    int8_t* w8 = (int8_t*)d_ws + W8_OFF;

    const int grid = (T_DIM / BM) * (N_DIM / BN);
    prep_kernel<<<T_DIM / 4 + (N_DIM * (K_DIM / 16)) / 256, 256, 0, stream>>>(
        x, xq, xs, w32, w8);
    // ablation probes first (scribble out), full kernel LAST (writes final out)
    gemm_i8_kernel<1><<<grid, 512, 0, stream>>>(xq, w8, xs, wsc, bias, out);
    gemm_i8_kernel<2><<<grid, 512, 0, stream>>>(xq, w8, xs, wsc, bias, out);
    gemm_i8_kernel<3><<<grid, 512, 0, stream>>>(xq, w8, xs, wsc, bias, out);
    gemm_i8_kernel<0><<<grid, 512, 0, stream>>>(xq, w8, xs, wsc, bias, out);
}

// Round 26
// 632.906 us; speedup vs baseline: 1.1114x; 1.1114x over previous
//
#include <hip/hip_runtime.h>
#include <hip/hip_bf16.h>
#include <stdint.h>

#define T_DIM 4096
#define K_DIM 4096
#define N_DIM 11008

#define XQ_OFF 0
#define XS_OFF 16777216
#define W8_OFF 16793600

typedef __attribute__((ext_vector_type(4))) int v4i;

// ---------------------------------------------------------------------------
// Kernel 1: FUSED quant + pack (grid-split, r21-r25-verified).
// ---------------------------------------------------------------------------
__global__ __launch_bounds__(256) void prep_kernel(
    const float* __restrict__ x, int8_t* __restrict__ xq, float* __restrict__ xs,
    const int* __restrict__ w32, int8_t* __restrict__ w8)
{
    if (blockIdx.x < T_DIM / 4) {
        const int wid   = threadIdx.x >> 6;
        const int lane  = threadIdx.x & 63;
        const int token = blockIdx.x * 4 + wid;

        const float* xrow = x + (size_t)token * K_DIM;

        float4 v[16];
        float am = 0.0f;
#pragma unroll
        for (int j = 0; j < 16; ++j) {
            v[j] = *(const float4*)(xrow + (size_t)(j * 64 + lane) * 4);
            am = fmaxf(am, fmaxf(fmaxf(fabsf(v[j].x), fabsf(v[j].y)),
                                 fmaxf(fabsf(v[j].z), fabsf(v[j].w))));
        }
#pragma unroll
        for (int m = 1; m < 64; m <<= 1)
            am = fmaxf(am, __shfl_xor(am, m, 64));

        const float scale = fmaxf(am, 1e-5f) / 127.0f;
        if (lane == 0) xs[token] = scale;

        uint32_t* qrow = (uint32_t*)(xq + (size_t)token * K_DIM);
#pragma unroll
        for (int j = 0; j < 16; ++j) {
            int q0 = min(127, max(-127, (int)rintf(v[j].x / scale)));
            int q1 = min(127, max(-127, (int)rintf(v[j].y / scale)));
            int q2 = min(127, max(-127, (int)rintf(v[j].z / scale)));
            int q3 = min(127, max(-127, (int)rintf(v[j].w / scale)));
            qrow[j * 64 + lane] = ((uint32_t)(uint8_t)(int8_t)q0)       |
                                  ((uint32_t)(uint8_t)(int8_t)q1 << 8)  |
                                  ((uint32_t)(uint8_t)(int8_t)q2 << 16) |
                                  ((uint32_t)(uint8_t)(int8_t)q3 << 24);
        }
    } else {
        const size_t tid = (size_t)(blockIdx.x - T_DIM / 4) * 256 + threadIdx.x;
        const int4* src = (const int4*)w32 + tid * 4;
        uint32_t o[4];
#pragma unroll
        for (int i = 0; i < 4; ++i) {
            int4 a = src[i];
            o[i] = ((uint32_t)a.x & 0xFFu) | (((uint32_t)a.y & 0xFFu) << 8) |
                   (((uint32_t)a.z & 0xFFu) << 16) | ((uint32_t)a.w << 24);
        }
        *(uint4*)(w8 + tid * 16) = make_uint4(o[0], o[1], o[2], o[3]);
    }
}

// ---------------------------------------------------------------------------
// Kernel 2: int8 MFMA GEMM — 256x256, BK=128B. r25 ablation showed staging DMA
// is the critical path => B bypasses LDS: per-wave direct global->register
// fragments (L2-served, 64B-coalesced row groups), double-buffered via
// manually 2x-unrolled loop (static indexing). A stays in LDS (2 x 32KB,
// shared across wn-waves). DMA insts/tile halved. Epilogue = r17-r25 verbatim.
// ---------------------------------------------------------------------------
#define BM 256
#define BN 256
#define BKB 128
#define NT (K_DIM / BKB)     // 32
#define A_SZ 32768           // 256 rows x 128 B

__global__ __launch_bounds__(512, 2) void gemm_i8_kernel(
    const int8_t* __restrict__ xq, const int8_t* __restrict__ w8,
    const float* __restrict__ xs, const float* __restrict__ wsc,
    const __hip_bfloat16* __restrict__ bias, float* __restrict__ out)
{
    __shared__ int8_t lds[2 * A_SZ];   // 64 KiB, A only

    constexpr int NBN = N_DIM / BN;              // 43
    constexpr int NWG = (T_DIM / BM) * NBN;      // 688
    constexpr int CPX = NWG / 8;                 // 86

    const int bid = blockIdx.x;
    const int b2  = (bid % 8) * CPX + bid / 8;
    const int bm  = b2 / NBN;
    const int bn  = b2 % NBN;

    const int tid  = threadIdx.x;
    const int wid  = tid >> 6;
    const int lane = tid & 63;
    const int wm   = wid >> 2;    // 0..1 (M)
    const int wn   = wid & 3;     // 0..3 (N)

    const int fr = lane & 15, kg = lane >> 4;

    // A fragment LDS offsets (chunk-XOR swizzle, r24-verified)
    int offA[8][2];
#pragma unroll
    for (int mi = 0; mi < 8; ++mi) {
        const int row = wm * 128 + mi * 16 + fr;
#pragma unroll
        for (int ks = 0; ks < 2; ++ks)
            offA[mi][ks] = row * 128 + (((ks * 4 + kg) ^ (row & 7)) << 4);
    }

    // B fragment global base pointers (per lane): row = bn*BN + wn*64+ni*16+fr
    const int8_t* gBf[4];
#pragma unroll
    for (int ni = 0; ni < 4; ++ni)
        gBf[ni] = w8 + (size_t)(bn * BN + wn * 64 + ni * 16 + fr) * K_DIM + kg * 16;

    // A staging (pre-swizzled source, r24-verified)
    const int srow  = tid >> 3;
    const int sslot = tid & 7;
    const int csw   = (sslot ^ (srow & 7)) * 16;
    const int8_t* gA = xq + (size_t)(bm * BM + srow) * K_DIM + csw;
    const int ldsBase = wid * 1024;

    v4i acc[8][4];
#pragma unroll
    for (int mi = 0; mi < 8; ++mi)
#pragma unroll
        for (int ni = 0; ni < 4; ++ni) acc[mi][ni] = (v4i){0, 0, 0, 0};

#define STAGE_A(bufb, kt)                                                       \
    do {                                                                        \
        _Pragma("unroll")                                                       \
        for (int r = 0; r < 4; ++r)                                             \
            __builtin_amdgcn_global_load_lds(                                   \
                (const __attribute__((address_space(1))) void*)(                \
                    gA + (size_t)r * 64 * K_DIM + (size_t)(kt) * BKB),          \
                (__attribute__((address_space(3))) void*)(                      \
                    lds + (bufb) * A_SZ + r * 8192 + ldsBase),                  \
                16, 0, 0);                                                      \
    } while (0)

#define LOAD_B(dst, kt)                                                         \
    do {                                                                        \
        _Pragma("unroll")                                                       \
        for (int ni = 0; ni < 4; ++ni) {                                        \
            dst[ni][0] = *(const v4i*)(gBf[ni] + (size_t)(kt) * BKB);           \
            dst[ni][1] = *(const v4i*)(gBf[ni] + (size_t)(kt) * BKB + 64);      \
        }                                                                       \
    } while (0)

    // body: compute tile t from A-buf `ab` and B regs BC; prefetch t+1 into
    // A-buf ab^1 and B regs BNx.
#define TILE_BODY(t, ab, BC, BNx)                                               \
    do {                                                                        \
        if ((t) + 1 < NT) { LOAD_B(BNx, (t) + 1); STAGE_A((ab) ^ 1, (t) + 1); } \
        const int8_t* bA = lds + (ab) * A_SZ;                                   \
        _Pragma("unroll")                                                       \
        for (int ks = 0; ks < 2; ++ks) {                                        \
            v4i aF[8];                                                          \
            _Pragma("unroll")                                                   \
            for (int mi = 0; mi < 8; ++mi)                                      \
                aF[mi] = *(const v4i*)(bA + offA[mi][ks]);                      \
            __builtin_amdgcn_s_setprio(1);                                      \
            _Pragma("unroll")                                                   \
            for (int mi = 0; mi < 8; ++mi)                                      \
                _Pragma("unroll")                                               \
                for (int ni = 0; ni < 4; ++ni)                                  \
                    acc[mi][ni] = __builtin_amdgcn_mfma_i32_16x16x64_i8(        \
                        aF[mi], BC[ni][ks], acc[mi][ni], 0, 0, 0);              \
            __builtin_amdgcn_s_setprio(0);                                      \
        }                                                                       \
        asm volatile("s_waitcnt vmcnt(0)" ::: "memory");                        \
        __builtin_amdgcn_s_barrier();                                           \
        asm volatile("" ::: "memory");                                          \
    } while (0)

    v4i B0[4][2], B1[4][2];

    // prologue: tile 0 -> A-buf 0 + B0 regs
    LOAD_B(B0, 0);
    STAGE_A(0, 0);
    asm volatile("s_waitcnt vmcnt(0)" ::: "memory");
    __builtin_amdgcn_s_barrier();
    asm volatile("" ::: "memory");

    // NT = 32 (even): manual 2x unroll for static B-buffer indexing
    for (int t = 0; t < NT; t += 2) {
        TILE_BODY(t,     0, B0, B1);
        TILE_BODY(t + 1, 1, B1, B0);
    }

    // epilogue (r17-r25-verified mapping; bf16-exact values in f32 slots)
    const int row0 = bm * BM + wm * 128 + (lane >> 4) * 4;
    const int col0 = bn * BN + wn * 64 + (lane & 15);
#pragma unroll
    for (int mi = 0; mi < 8; ++mi) {
#pragma unroll
        for (int j = 0; j < 4; ++j) {
            const int row = row0 + mi * 16 + j;
            const float xscale = xs[row];
#pragma unroll
            for (int ni = 0; ni < 4; ++ni) {
                const int col = col0 + ni * 16;
                float p_  = (float)acc[mi][ni][j] * xscale * wsc[col];
                float pb_ = __bfloat162float(__float2bfloat16(p_));
                float vb  = __bfloat162float(__float2bfloat16(
                                pb_ + __bfloat162float(bias[col])));
                out[(size_t)row * N_DIM + col] = vb;
            }
        }
    }
#undef STAGE_A
#undef LOAD_B
#undef TILE_BODY
}

// ---------------------------------------------------------------------------
extern "C" void kernel_launch(void* const* d_in, const int* in_sizes, int n_in,
                              void* d_out, int out_size, void* d_ws, size_t ws_size,
                              hipStream_t stream)
{
    const float*          x    = (const float*)d_in[0];
    const int*            w32  = (const int*)d_in[1];
    const float*          wsc  = (const float*)d_in[2];
    const __hip_bfloat16* bias = (const __hip_bfloat16*)d_in[3];
    float*                out  = (float*)d_out;

    int8_t* xq = (int8_t*)d_ws + XQ_OFF;
    float*  xs = (float*)((char*)d_ws + XS_OFF);
    int8_t* w8 = (int8_t*)d_ws + W8_OFF;

    prep_kernel<<<T_DIM / 4 + (N_DIM * (K_DIM / 16)) / 256, 256, 0, stream>>>(
        x, xq, xs, w32, w8);
    gemm_i8_kernel<<<(T_DIM / BM) * (N_DIM / BN), 512, 0, stream>>>(
        xq, w8, xs, wsc, bias, out);
}

// Round 27
// 274.073 us; speedup vs baseline: 2.5665x; 2.3093x over previous
//
#include <hip/hip_runtime.h>
#include <hip/hip_bf16.h>
#include <stdint.h>

#define T_DIM 4096
#define K_DIM 4096
#define N_DIM 11008

#define XQ_OFF 0
#define XS_OFF 16777216
#define W8_OFF 16793600

typedef __attribute__((ext_vector_type(4)))  int v4i;
typedef __attribute__((ext_vector_type(16))) int v16i;

// ---------------------------------------------------------------------------
// Kernel 1: FUSED quant + pack (grid-split, r21-r25-verified).
// ---------------------------------------------------------------------------
__global__ __launch_bounds__(256) void prep_kernel(
    const float* __restrict__ x, int8_t* __restrict__ xq, float* __restrict__ xs,
    const int* __restrict__ w32, int8_t* __restrict__ w8)
{
    if (blockIdx.x < T_DIM / 4) {
        const int wid   = threadIdx.x >> 6;
        const int lane  = threadIdx.x & 63;
        const int token = blockIdx.x * 4 + wid;

        const float* xrow = x + (size_t)token * K_DIM;

        float4 v[16];
        float am = 0.0f;
#pragma unroll
        for (int j = 0; j < 16; ++j) {
            v[j] = *(const float4*)(xrow + (size_t)(j * 64 + lane) * 4);
            am = fmaxf(am, fmaxf(fmaxf(fabsf(v[j].x), fabsf(v[j].y)),
                                 fmaxf(fabsf(v[j].z), fabsf(v[j].w))));
        }
#pragma unroll
        for (int m = 1; m < 64; m <<= 1)
            am = fmaxf(am, __shfl_xor(am, m, 64));

        const float scale = fmaxf(am, 1e-5f) / 127.0f;
        if (lane == 0) xs[token] = scale;

        uint32_t* qrow = (uint32_t*)(xq + (size_t)token * K_DIM);
#pragma unroll
        for (int j = 0; j < 16; ++j) {
            int q0 = min(127, max(-127, (int)rintf(v[j].x / scale)));
            int q1 = min(127, max(-127, (int)rintf(v[j].y / scale)));
            int q2 = min(127, max(-127, (int)rintf(v[j].z / scale)));
            int q3 = min(127, max(-127, (int)rintf(v[j].w / scale)));
            qrow[j * 64 + lane] = ((uint32_t)(uint8_t)(int8_t)q0)       |
                                  ((uint32_t)(uint8_t)(int8_t)q1 << 8)  |
                                  ((uint32_t)(uint8_t)(int8_t)q2 << 16) |
                                  ((uint32_t)(uint8_t)(int8_t)q3 << 24);
        }
    } else {
        const size_t tid = (size_t)(blockIdx.x - T_DIM / 4) * 256 + threadIdx.x;
        const int4* src = (const int4*)w32 + tid * 4;
        uint32_t o[4];
#pragma unroll
        for (int i = 0; i < 4; ++i) {
            int4 a = src[i];
            o[i] = ((uint32_t)a.x & 0xFFu) | (((uint32_t)a.y & 0xFFu) << 8) |
                   (((uint32_t)a.z & 0xFFu) << 16) | ((uint32_t)a.w << 24);
        }
        *(uint4*)(w8 + tid * 16) = make_uint4(o[0], o[1], o[2], o[3]);
    }
}

// ---------------------------------------------------------------------------
// Kernel 2: int8 MFMA GEMM — r24 skeleton (256x256, BK=128B, 2-buf dist-1,
// chunk-XOR swizzle, 1 block/CU) with MFMA shape 32x32x32 (half the insts,
// 4404-TOPS ceiling). A/B share identical lane->(row,chunk) maps (k-perms
// cancel); C/D map col=lane&31, row=(reg&3)+8*(reg>>2)+4*(lane>>5) (m74).
// ---------------------------------------------------------------------------
#define BM 256
#define BN 256
#define BKB 128
#define NT (K_DIM / BKB)     // 32
#define MAT_SZ 32768         // 256 rows x 128 B

__global__ __launch_bounds__(512, 2) void gemm_i8_kernel(
    const int8_t* __restrict__ xq, const int8_t* __restrict__ w8,
    const float* __restrict__ xs, const float* __restrict__ wsc,
    const __hip_bfloat16* __restrict__ bias, float* __restrict__ out)
{
    __shared__ int8_t lds[2 * 2 * MAT_SZ];   // 128 KiB

    constexpr int NBN = N_DIM / BN;              // 43
    constexpr int NWG = (T_DIM / BM) * NBN;      // 688
    constexpr int CPX = NWG / 8;                 // 86

    const int bid = blockIdx.x;
    const int b2  = (bid % 8) * CPX + bid / 8;   // bijective XCD swizzle
    const int bm  = b2 / NBN;
    const int bn  = b2 % NBN;

    const int tid  = threadIdx.x;
    const int wid  = tid >> 6;
    const int lane = tid & 63;
    const int wm   = wid >> 2;    // 0..1 (M)
    const int wn   = wid & 3;     // 0..3 (N)

    // 32x32 fragment addressing: row_in_frag = lane&31, k-half = lane>>5.
    // LDS offset = row*128 + ((chunk ^ (row&7)) << 4), chunk = ks*2 + khalf.
    const int fr32 = lane & 31;
    const int kh   = lane >> 5;
    int offA[4][4], offB[2][4];
#pragma unroll
    for (int mi = 0; mi < 4; ++mi) {
        const int row = wm * 128 + mi * 32 + fr32;
#pragma unroll
        for (int ks = 0; ks < 4; ++ks)
            offA[mi][ks] = row * 128 + (((ks * 2 + kh) ^ (row & 7)) << 4);
    }
#pragma unroll
    for (int ni = 0; ni < 2; ++ni) {
        const int row = wn * 64 + ni * 32 + fr32;
#pragma unroll
        for (int ks = 0; ks < 4; ++ks)
            offB[ni][ks] = row * 128 + (((ks * 2 + kh) ^ (row & 7)) << 4);
    }

    // staging (pre-swizzled source, r24-verified)
    const int srow  = tid >> 3;
    const int sslot = tid & 7;
    const int csw   = (sslot ^ (srow & 7)) * 16;
    const int8_t* gA = xq + (size_t)(bm * BM + srow) * K_DIM + csw;
    const int8_t* gB = w8 + (size_t)(bn * BN + srow) * K_DIM + csw;
    const int ldsBase = wid * 1024;

    v16i acc[4][2];
#pragma unroll
    for (int mi = 0; mi < 4; ++mi)
#pragma unroll
        for (int ni = 0; ni < 2; ++ni)
#pragma unroll
            for (int r = 0; r < 16; ++r) acc[mi][ni][r] = 0;

#define STAGE(bufb, mat, r, kt)                                                 \
    __builtin_amdgcn_global_load_lds(                                           \
        (const __attribute__((address_space(1))) void*)(                        \
            ((mat) ? gB : gA) + (size_t)(r) * 64 * K_DIM + (size_t)(kt) * BKB), \
        (__attribute__((address_space(3))) void*)(                              \
            lds + ((bufb) * 2 + (mat)) * MAT_SZ + (r) * 8192 + ldsBase),        \
        16, 0, 0)

#define STAGE_TILE(bufb, kt)                                                    \
    do {                                                                        \
        STAGE(bufb, 0, 0, kt); STAGE(bufb, 0, 1, kt);                           \
        STAGE(bufb, 0, 2, kt); STAGE(bufb, 0, 3, kt);                           \
        STAGE(bufb, 1, 0, kt); STAGE(bufb, 1, 1, kt);                           \
        STAGE(bufb, 1, 2, kt); STAGE(bufb, 1, 3, kt);                           \
    } while (0)

    STAGE_TILE(0, 0);
    asm volatile("s_waitcnt vmcnt(0)" ::: "memory");
    __builtin_amdgcn_s_barrier();
    asm volatile("" ::: "memory");

    for (int t = 0; t < NT; ++t) {
        const int b  = t & 1;
        const int pn = b ^ 1;
        const int8_t* bA = lds + (b * 2 + 0) * MAT_SZ;
        const int8_t* bB = lds + (b * 2 + 1) * MAT_SZ;

        if (t + 1 < NT) STAGE_TILE(pn, t + 1);

#pragma unroll
        for (int ks = 0; ks < 4; ++ks) {
            v4i aF[4], bF[2];
#pragma unroll
            for (int ni = 0; ni < 2; ++ni)
                bF[ni] = *(const v4i*)(bB + offB[ni][ks]);
#pragma unroll
            for (int mi = 0; mi < 4; ++mi)
                aF[mi] = *(const v4i*)(bA + offA[mi][ks]);

            __builtin_amdgcn_s_setprio(1);
#pragma unroll
            for (int mi = 0; mi < 4; ++mi)
#pragma unroll
                for (int ni = 0; ni < 2; ++ni)
                    acc[mi][ni] = __builtin_amdgcn_mfma_i32_32x32x32_i8(
                        aF[mi], bF[ni], acc[mi][ni], 0, 0, 0);
            __builtin_amdgcn_s_setprio(0);
        }

        asm volatile("s_waitcnt vmcnt(0)" ::: "memory");
        __builtin_amdgcn_s_barrier();
        asm volatile("" ::: "memory");
    }

    // epilogue — 32x32 C/D map (m74/m101, dtype-independent):
    //   col = lane&31, row = (reg&3) + 8*(reg>>2) + 4*(lane>>5)
    const int row0 = bm * BM + wm * 128;
    const int col0 = bn * BN + wn * 64 + fr32;
#pragma unroll
    for (int mi = 0; mi < 4; ++mi) {
#pragma unroll
        for (int r = 0; r < 16; ++r) {
            const int row = row0 + mi * 32 + (r & 3) + 8 * (r >> 2) + 4 * kh;
            const float xscale = xs[row];
#pragma unroll
            for (int ni = 0; ni < 2; ++ni) {
                const int col = col0 + ni * 32;
                float p_  = (float)acc[mi][ni][r] * xscale * wsc[col];
                float pb_ = __bfloat162float(__float2bfloat16(p_));
                float vb  = __bfloat162float(__float2bfloat16(
                                pb_ + __bfloat162float(bias[col])));
                out[(size_t)row * N_DIM + col] = vb;
            }
        }
    }
#undef STAGE
#undef STAGE_TILE
}

// ---------------------------------------------------------------------------
extern "C" void kernel_launch(void* const* d_in, const int* in_sizes, int n_in,
                              void* d_out, int out_size, void* d_ws, size_t ws_size,
                              hipStream_t stream)
{
    const float*          x    = (const float*)d_in[0];
    const int*            w32  = (const int*)d_in[1];
    const float*          wsc  = (const float*)d_in[2];
    const __hip_bfloat16* bias = (const __hip_bfloat16*)d_in[3];
    float*                out  = (float*)d_out;

    int8_t* xq = (int8_t*)d_ws + XQ_OFF;
    float*  xs = (float*)((char*)d_ws + XS_OFF);
    int8_t* w8 = (int8_t*)d_ws + W8_OFF;

    prep_kernel<<<T_DIM / 4 + (N_DIM * (K_DIM / 16)) / 256, 256, 0, stream>>>(
        x, xq, xs, w32, w8);
    gemm_i8_kernel<<<(T_DIM / BM) * (N_DIM / BN), 512, 0, stream>>>(
        xq, w8, xs, wsc, bias, out);
}

// Round 28
// 254.326 us; speedup vs baseline: 2.7657x; 1.0776x over previous
//
#include <hip/hip_runtime.h>
#include <hip/hip_bf16.h>
#include <stdint.h>

#define T_DIM 4096
#define K_DIM 4096
#define N_DIM 11008

#define XQ_OFF 0
#define XS_OFF 16777216
#define W8_OFF 16793600

typedef __attribute__((ext_vector_type(4))) int v4i;

// ---------------------------------------------------------------------------
// Kernel 1: FUSED quant + pack (grid-split, r21-r25-verified).
// ---------------------------------------------------------------------------
__global__ __launch_bounds__(256) void prep_kernel(
    const float* __restrict__ x, int8_t* __restrict__ xq, float* __restrict__ xs,
    const int* __restrict__ w32, int8_t* __restrict__ w8)
{
    if (blockIdx.x < T_DIM / 4) {
        const int wid   = threadIdx.x >> 6;
        const int lane  = threadIdx.x & 63;
        const int token = blockIdx.x * 4 + wid;

        const float* xrow = x + (size_t)token * K_DIM;

        float4 v[16];
        float am = 0.0f;
#pragma unroll
        for (int j = 0; j < 16; ++j) {
            v[j] = *(const float4*)(xrow + (size_t)(j * 64 + lane) * 4);
            am = fmaxf(am, fmaxf(fmaxf(fabsf(v[j].x), fabsf(v[j].y)),
                                 fmaxf(fabsf(v[j].z), fabsf(v[j].w))));
        }
#pragma unroll
        for (int m = 1; m < 64; m <<= 1)
            am = fmaxf(am, __shfl_xor(am, m, 64));

        const float scale = fmaxf(am, 1e-5f) / 127.0f;
        if (lane == 0) xs[token] = scale;

        uint32_t* qrow = (uint32_t*)(xq + (size_t)token * K_DIM);
#pragma unroll
        for (int j = 0; j < 16; ++j) {
            int q0 = min(127, max(-127, (int)rintf(v[j].x / scale)));
            int q1 = min(127, max(-127, (int)rintf(v[j].y / scale)));
            int q2 = min(127, max(-127, (int)rintf(v[j].z / scale)));
            int q3 = min(127, max(-127, (int)rintf(v[j].w / scale)));
            qrow[j * 64 + lane] = ((uint32_t)(uint8_t)(int8_t)q0)       |
                                  ((uint32_t)(uint8_t)(int8_t)q1 << 8)  |
                                  ((uint32_t)(uint8_t)(int8_t)q2 << 16) |
                                  ((uint32_t)(uint8_t)(int8_t)q3 << 24);
        }
    } else {
        const size_t tid = (size_t)(blockIdx.x - T_DIM / 4) * 256 + threadIdx.x;
        const int4* src = (const int4*)w32 + tid * 4;
        uint32_t o[4];
#pragma unroll
        for (int i = 0; i < 4; ++i) {
            int4 a = src[i];
            o[i] = ((uint32_t)a.x & 0xFFu) | (((uint32_t)a.y & 0xFFu) << 8) |
                   (((uint32_t)a.z & 0xFFu) << 16) | ((uint32_t)a.w << 24);
        }
        *(uint4*)(w8 + tid * 16) = make_uint4(o[0], o[1], o[2], o[3]);
    }
}

// ---------------------------------------------------------------------------
// Kernel 2: int8 MFMA GEMM — r24 exact (verified optimum: 203us GEMM).
// 256x256 tile, BK=128B, 16x16x64 MFMA, 2-buf distance-1, chunk-XOR swizzle
// (2-way = free on 16-row fragment reads), single barrier per K-tile,
// setprio around MFMA, bijective XCD swizzle. Epilogue r17-verified.
// ---------------------------------------------------------------------------
#define BM 256
#define BN 256
#define BKB 128
#define NT (K_DIM / BKB)     // 32
#define MAT_SZ 32768         // 256 rows x 128 B

__global__ __launch_bounds__(512, 2) void gemm_i8_kernel(
    const int8_t* __restrict__ xq, const int8_t* __restrict__ w8,
    const float* __restrict__ xs, const float* __restrict__ wsc,
    const __hip_bfloat16* __restrict__ bias, float* __restrict__ out)
{
    __shared__ int8_t lds[2 * 2 * MAT_SZ];   // 128 KiB

    constexpr int NBN = N_DIM / BN;              // 43
    constexpr int NWG = (T_DIM / BM) * NBN;      // 688
    constexpr int CPX = NWG / 8;                 // 86

    const int bid = blockIdx.x;
    const int b2  = (bid % 8) * CPX + bid / 8;
    const int bm  = b2 / NBN;
    const int bn  = b2 % NBN;

    const int tid  = threadIdx.x;
    const int wid  = tid >> 6;
    const int lane = tid & 63;
    const int wm   = wid >> 2;
    const int wn   = wid & 3;

    const int fr = lane & 15, kg = lane >> 4;
    int offA[8][2], offB[4][2];
#pragma unroll
    for (int mi = 0; mi < 8; ++mi) {
        const int row = wm * 128 + mi * 16 + fr;
#pragma unroll
        for (int ks = 0; ks < 2; ++ks)
            offA[mi][ks] = row * 128 + (((ks * 4 + kg) ^ (row & 7)) << 4);
    }
#pragma unroll
    for (int ni = 0; ni < 4; ++ni) {
        const int row = wn * 64 + ni * 16 + fr;
#pragma unroll
        for (int ks = 0; ks < 2; ++ks)
            offB[ni][ks] = row * 128 + (((ks * 4 + kg) ^ (row & 7)) << 4);
    }

    const int srow  = tid >> 3;
    const int sslot = tid & 7;
    const int csw   = (sslot ^ (srow & 7)) * 16;
    const int8_t* gA = xq + (size_t)(bm * BM + srow) * K_DIM + csw;
    const int8_t* gB = w8 + (size_t)(bn * BN + srow) * K_DIM + csw;
    const int ldsBase = wid * 1024;

    v4i acc[8][4];
#pragma unroll
    for (int mi = 0; mi < 8; ++mi)
#pragma unroll
        for (int ni = 0; ni < 4; ++ni) acc[mi][ni] = (v4i){0, 0, 0, 0};

#define STAGE(bufb, mat, r, kt)                                                 \
    __builtin_amdgcn_global_load_lds(                                           \
        (const __attribute__((address_space(1))) void*)(                        \
            ((mat) ? gB : gA) + (size_t)(r) * 64 * K_DIM + (size_t)(kt) * BKB), \
        (__attribute__((address_space(3))) void*)(                              \
            lds + ((bufb) * 2 + (mat)) * MAT_SZ + (r) * 8192 + ldsBase),        \
        16, 0, 0)

#define STAGE_TILE(bufb, kt)                                                    \
    do {                                                                        \
        STAGE(bufb, 0, 0, kt); STAGE(bufb, 0, 1, kt);                           \
        STAGE(bufb, 0, 2, kt); STAGE(bufb, 0, 3, kt);                           \
        STAGE(bufb, 1, 0, kt); STAGE(bufb, 1, 1, kt);                           \
        STAGE(bufb, 1, 2, kt); STAGE(bufb, 1, 3, kt);                           \
    } while (0)

    STAGE_TILE(0, 0);
    asm volatile("s_waitcnt vmcnt(0)" ::: "memory");
    __builtin_amdgcn_s_barrier();
    asm volatile("" ::: "memory");

    for (int t = 0; t < NT; ++t) {
        const int b  = t & 1;
        const int pn = b ^ 1;
        const int8_t* bA = lds + (b * 2 + 0) * MAT_SZ;
        const int8_t* bB = lds + (b * 2 + 1) * MAT_SZ;

        if (t + 1 < NT) STAGE_TILE(pn, t + 1);

#pragma unroll
        for (int ks = 0; ks < 2; ++ks) {
            v4i bF[4], aF[8];
#pragma unroll
            for (int ni = 0; ni < 4; ++ni)
                bF[ni] = *(const v4i*)(bB + offB[ni][ks]);
#pragma unroll
            for (int mi = 0; mi < 8; ++mi)
                aF[mi] = *(const v4i*)(bA + offA[mi][ks]);

            __builtin_amdgcn_s_setprio(1);
#pragma unroll
            for (int mi = 0; mi < 8; ++mi)
#pragma unroll
                for (int ni = 0; ni < 4; ++ni)
                    acc[mi][ni] = __builtin_amdgcn_mfma_i32_16x16x64_i8(
                        aF[mi], bF[ni], acc[mi][ni], 0, 0, 0);
            __builtin_amdgcn_s_setprio(0);
        }

        asm volatile("s_waitcnt vmcnt(0)" ::: "memory");
        __builtin_amdgcn_s_barrier();
        asm volatile("" ::: "memory");
    }

    const int row0 = bm * BM + wm * 128 + (lane >> 4) * 4;
    const int col0 = bn * BN + wn * 64 + (lane & 15);
#pragma unroll
    for (int mi = 0; mi < 8; ++mi) {
#pragma unroll
        for (int j = 0; j < 4; ++j) {
            const int row = row0 + mi * 16 + j;
            const float xscale = xs[row];
#pragma unroll
            for (int ni = 0; ni < 4; ++ni) {
                const int col = col0 + ni * 16;
                float p_  = (float)acc[mi][ni][j] * xscale * wsc[col];
                float pb_ = __bfloat162float(__float2bfloat16(p_));
                float vb  = __bfloat162float(__float2bfloat16(
                                pb_ + __bfloat162float(bias[col])));
                out[(size_t)row * N_DIM + col] = vb;
            }
        }
    }
#undef STAGE
#undef STAGE_TILE
}

// ---------------------------------------------------------------------------
extern "C" void kernel_launch(void* const* d_in, const int* in_sizes, int n_in,
                              void* d_out, int out_size, void* d_ws, size_t ws_size,
                              hipStream_t stream)
{
    const float*          x    = (const float*)d_in[0];
    const int*            w32  = (const int*)d_in[1];
    const float*          wsc  = (const float*)d_in[2];
    const __hip_bfloat16* bias = (const __hip_bfloat16*)d_in[3];
    float*                out  = (float*)d_out;

    int8_t* xq = (int8_t*)d_ws + XQ_OFF;
    float*  xs = (float*)((char*)d_ws + XS_OFF);
    int8_t* w8 = (int8_t*)d_ws + W8_OFF;

    prep_kernel<<<T_DIM / 4 + (N_DIM * (K_DIM / 16)) / 256, 256, 0, stream>>>(
        x, xq, xs, w32, w8);
    gemm_i8_kernel<<<(T_DIM / BM) * (N_DIM / BN), 512, 0, stream>>>(
        xq, w8, xs, wsc, bias, out);
}